// Round 16
// baseline (86.466 us; speedup 1.0000x reference)
//
#include <hip/hip_runtime.h>

typedef __attribute__((ext_vector_type(8))) short short8;
typedef __attribute__((ext_vector_type(4))) float f32x4;
typedef __attribute__((ext_vector_type(16))) float f32x16;
typedef __attribute__((ext_vector_type(4))) unsigned short ushort4v;
typedef __attribute__((ext_vector_type(4))) unsigned int u32x4;
typedef unsigned short u16;
typedef unsigned int u32;

#define NN 1024
#define DD 512
#define DH 64
#define EXP2C 0.18033688f   /* 0.125 * log2(e) */

// ---------- helpers ----------

__device__ __forceinline__ u16 f2bf(float f) {
    unsigned u = __float_as_uint(f);
    u += 0x7fffu + ((u >> 16) & 1u);   // RNE
    return (u16)(u >> 16);
}

// native hardware exp2 (1 VALU op)
__device__ __forceinline__ float fexp2(float x) {
    float r;
    asm("v_exp_f32 %0, %1" : "=v"(r) : "v"(x));
    return r;
}

// packed fp32 pair -> bf16 pair (RNE), single VALU op
__device__ __forceinline__ u32 cvtpk(float a, float b) {
    u32 r;
    asm("v_cvt_pk_bf16_f32 %0, %1, %2" : "=v"(r) : "v"(a), "v"(b));
    return r;
}

__device__ __forceinline__ void stage_gll(const char* src, char* dst) {
    __builtin_amdgcn_global_load_lds(
        (const __attribute__((address_space(1))) unsigned int*)src,
        (__attribute__((address_space(3))) unsigned int*)dst, 16, 0, 0);
}

__device__ __forceinline__ short8 lds_ld128(const char* base, int row, int colbyte) {
    int off = (row * 128 + colbyte) ^ ((row & 7) << 4);
    return *(const short8*)(base + off);
}

__device__ __forceinline__ void stage128x64(const u16* g, int ldRow, char* lds,
                                            int wid, int lane) {
#pragma unroll
    for (int r = 0; r < 4; ++r) {
        int cidx = (r * 4 + wid) * 64 + lane;
        int row  = cidx >> 3;
        int ch   = (cidx & 7) ^ (row & 7);
        stage_gll((const char*)(g + row * ldRow) + ch * 16, lds + (r * 4 + wid) * 1024);
    }
}

// fold-2 tile (32 rows x 128B, 4KB): lane-offset for (il,hh,t) — p-invariant
__device__ __forceinline__ int offF2(int il, int hh, int t) {
    int c0 = t * 2 + hh;
    return ((il >> 1) << 8) + ((il & 1) << 7) + ((c0 ^ ((il >> 1) & 7)) << 4);
}

// fold-4 tile (64 rows x 64B, 4KB): lane-offset for (il,hh,m,tc)
__device__ __forceinline__ int offF4(int il, int hh, int m, int tc) {
    int c0 = tc * 2 + hh;
    int line = m * 8 + (il >> 2);
    int s16 = (((il & 3) << 2) + c0) ^ ((il >> 2) & 7);
    return line * 256 + (s16 << 4);
}

// ---------- fused fp32 -> bf16 convert ----------
__global__ void f2bf_all(const float* __restrict__ x, const float* __restrict__ ctx,
                         const float* __restrict__ Wq, const float* __restrict__ Wk,
                         const float* __restrict__ Wv, const float* __restrict__ Wo,
                         u16* __restrict__ xb, u16* __restrict__ cb,
                         u16* __restrict__ wb) {
    int i = blockIdx.x * blockDim.x + threadIdx.x;   // float4 index, 2359296 total
    const float* src;
    u16* dst;
    int off;
    if (i < 1048576)      { src = x;   dst = xb; off = i; }
    else if (i < 2097152) { src = ctx; dst = cb; off = i - 1048576; }
    else {
        int wi = i - 2097152;
        int which = wi >> 16;
        off = wi & 65535;
        dst = wb + (size_t)which * 262144;
        src = (which == 0) ? Wq : (which == 1) ? Wk : (which == 2) ? Wv : Wo;
    }
    float4 v = ((const float4*)src)[off];
    ushort4v o;
    o.x = f2bf(v.x); o.y = f2bf(v.y); o.z = f2bf(v.z); o.w = f2bf(v.w);
    *(ushort4v*)(dst + (size_t)off * 4) = o;
}

// ---------- fused QKV projection GEMMs ----------
// serial 32KB stage, 3 blocks/CU: all 768 blocks co-resident (no capacity tail)
__global__ __launch_bounds__(256, 3) void gemm_qkv(
    const u16* __restrict__ xb, const u16* __restrict__ cb, const u16* __restrict__ wb,
    u16* __restrict__ qb, u16* __restrict__ kb, u16* __restrict__ vT)
{
    __shared__ char As[16384];
    __shared__ char Bs[16384];
    const int z = blockIdx.z;
    const u16* A = (z == 0) ? xb : cb;
    const u16* B = wb + (size_t)z * 262144;
    const int lane = threadIdx.x & 63;
    const int wid  = threadIdx.x >> 6;
    const int wr = wid >> 1, wc = wid & 1;
    const int n = blockIdx.x + 4 * blockIdx.y;
    const int L = (n & 7) * 32 + (n >> 3);
    const int rowBase = (L >> 2) * 128;
    const int colBase = (L & 3) * 128;

    f32x4 acc[4][4] = {};
    for (int kt = 0; kt < 8; ++kt) {
        __syncthreads();
        stage128x64(A + (size_t)rowBase * DD + kt * 64, DD, As, wid, lane);
        stage128x64(B + (size_t)colBase * DD + kt * 64, DD, Bs, wid, lane);
        __syncthreads();
#pragma unroll
        for (int kk = 0; kk < 2; ++kk) {
            const int cbb = kk * 64 + (lane >> 4) * 16;
            short8 af[4], bf[4];
#pragma unroll
            for (int m = 0; m < 4; ++m) af[m] = lds_ld128(As, wr * 64 + m * 16 + (lane & 15), cbb);
#pragma unroll
            for (int q = 0; q < 4; ++q) bf[q] = lds_ld128(Bs, wc * 64 + q * 16 + (lane & 15), cbb);
#pragma unroll
            for (int m = 0; m < 4; ++m) {
#pragma unroll
                for (int q = 0; q < 4; ++q)
                    acc[m][q] = __builtin_amdgcn_mfma_f32_16x16x32_bf16(af[m], bf[q], acc[m][q], 0, 0, 0);
            }
        }
    }
#pragma unroll
    for (int m = 0; m < 4; ++m) {
#pragma unroll
        for (int q = 0; q < 4; ++q) {
            const int r0 = rowBase + wr * 64 + m * 16 + ((lane >> 4) << 2);
            const int c  = colBase + wc * 64 + q * 16 + (lane & 15);
            if (z < 2) {
                u16* O = z ? kb : qb;
#pragma unroll
                for (int g = 0; g < 4; ++g) O[(size_t)(r0 + g) * DD + c] = f2bf(acc[m][q][g]);
            } else {
                ushort4v pk;
#pragma unroll
                for (int g = 0; g < 4; ++g) pk[g] = f2bf(acc[m][q][g]);
                *(ushort4v*)(vT + (size_t)c * 8192 + r0) = pk;
            }
        }
    }
}

// ---------- final GEMM: fp32 out + bias (double-buffered LDS pipeline) ----------
__global__ __launch_bounds__(256, 2) void gemm_out(
    const u16* __restrict__ A, const u16* __restrict__ B,
    float* __restrict__ Out, const float* __restrict__ bias)
{
    alignas(16) __shared__ char smem[65536];
    const int lane = threadIdx.x & 63;
    const int wid  = threadIdx.x >> 6;
    const int wr = wid >> 1, wc = wid & 1;
    const int n = blockIdx.x + 4 * blockIdx.y;
    const int L = (n & 7) * 32 + (n >> 3);
    const int rowBase = (L >> 2) * 128;
    const int colBase = (L & 3) * 128;
    const u16* Abase = A + (size_t)rowBase * DD;
    const u16* Bbase = B + (size_t)colBase * DD;

    f32x4 acc[4][4] = {};
    stage128x64(Abase, DD, smem, wid, lane);
    stage128x64(Bbase, DD, smem + 32768, wid, lane);
    for (int kt = 0; kt < 8; ++kt) {
        __syncthreads();
        char* curA = smem + (kt & 1) * 16384;
        char* curB = smem + 32768 + (kt & 1) * 16384;
        if (kt < 7) {
            stage128x64(Abase + (kt + 1) * 64, DD, smem + ((kt + 1) & 1) * 16384, wid, lane);
            stage128x64(Bbase + (kt + 1) * 64, DD, smem + 32768 + ((kt + 1) & 1) * 16384, wid, lane);
        }
#pragma unroll
        for (int kk = 0; kk < 2; ++kk) {
            const int cbb = kk * 64 + (lane >> 4) * 16;
            short8 af[4], bf[4];
#pragma unroll
            for (int m = 0; m < 4; ++m) af[m] = lds_ld128(curA, wr * 64 + m * 16 + (lane & 15), cbb);
#pragma unroll
            for (int q = 0; q < 4; ++q) bf[q] = lds_ld128(curB, wc * 64 + q * 16 + (lane & 15), cbb);
#pragma unroll
            for (int m = 0; m < 4; ++m) {
#pragma unroll
                for (int q = 0; q < 4; ++q)
                    acc[m][q] = __builtin_amdgcn_mfma_f32_16x16x32_bf16(af[m], bf[q], acc[m][q], 0, 0, 0);
            }
        }
    }
#pragma unroll
    for (int m = 0; m < 4; ++m) {
#pragma unroll
        for (int q = 0; q < 4; ++q) {
            const int r0 = rowBase + wr * 64 + m * 16 + ((lane >> 4) << 2);
            const int c  = colBase + wc * 64 + q * 16 + (lane & 15);
            const float bb = bias[c];
#pragma unroll
            for (int g = 0; g < 4; ++g) Out[(size_t)(r0 + g) * DD + c] = acc[m][q][g] + bb;
        }
    }
}

// ---------- pass 1: lic[j] = -log2( sum_i exp(sim) ) ----------
__global__ __launch_bounds__(256, 4) void colsum_k(
    const u16* __restrict__ qb, const u16* __restrict__ kb, float* __restrict__ lic)
{
    alignas(16) __shared__ char smem[16384];
    __shared__ float cs[128];
    const int tid = threadIdx.x;
    const int lane = tid & 63, wid = tid >> 6;
    const int il = lane & 31, hh = lane >> 5;
    const int n = blockIdx.x + 16 * blockIdx.y;
    const int L = (n & 7) * 128 + (n >> 3);
    const int jg = L & 15, bh = L >> 4;
    const int b = bh >> 3, h = bh & 7;
    const int jbp = wid & 1, ih = wid >> 1;
    const int jbase = jg * 64 + jbp * 32;

    const u16* kRow = kb + (size_t)(b * NN + jbase + il) * DD + h * DH + hh * 8;
    short8 kf[4];
#pragma unroll
    for (int t = 0; t < 4; ++t) kf[t] = *(const short8*)(kRow + t * 16);

    const int line = tid >> 4, s15 = tid & 15;
    const int slot8 = (s15 & 7) ^ (line & 7);
    const u16* qg0 = qb + (size_t)(b * NN) * DD + h * DH;
    const char* pQ0 = (const char*)(qg0 + (size_t)(line * 2 + (s15 >> 3)) * DD) + slot8 * 16;
    const char* pQ1 = pQ0 + 512 * DD * 2;
    const int dstoff = tid * 16;

    auto stageQ = [&](char* buf, const char* q0, const char* q1) {
        stage_gll(q0, buf + dstoff);
        stage_gll(q1, buf + 4096 + dstoff);
    };

    int oq[4];
#pragma unroll
    for (int t = 0; t < 4; ++t) oq[t] = offF2(il, hh, t) + ih * 4096;

    float cp[16] = {};
    stageQ(smem, pQ0, pQ1);
    pQ0 += 32768; pQ1 += 32768;
    for (int p = 0; p < 16; ++p) {
        char* buf = smem + (p & 1) * 8192;
        __syncthreads();
        if (p < 15) {
            stageQ(smem + ((p + 1) & 1) * 8192, pQ0, pQ1);
            pQ0 += 32768; pQ1 += 32768;
        }
        short8 qf[4];
#pragma unroll
        for (int t = 0; t < 4; ++t) qf[t] = *(const short8*)(buf + oq[t]);
        f32x16 sa = {};
        __builtin_amdgcn_s_setprio(1);
#pragma unroll
        for (int t = 0; t < 4; ++t)
            sa = __builtin_amdgcn_mfma_f32_32x32x16_bf16(kf[t], qf[t], sa, 0, 0, 0);
        __builtin_amdgcn_s_setprio(0);
#pragma unroll
        for (int r = 0; r < 16; ++r) cp[r] += fexp2(sa[r] * EXP2C);
    }
#pragma unroll
    for (int r = 0; r < 16; ++r) {
        cp[r] += __shfl_xor(cp[r], 1);
        cp[r] += __shfl_xor(cp[r], 2);
        cp[r] += __shfl_xor(cp[r], 4);
        cp[r] += __shfl_xor(cp[r], 8);
        cp[r] += __shfl_xor(cp[r], 16);
    }
    if (il == 0) {
#pragma unroll
        for (int r = 0; r < 16; ++r) cs[(jbp * 2 + ih) * 32 + hh * 16 + r] = cp[r];
    }
    __syncthreads();
    if (tid < 64) {
        int jbp2 = tid >> 5, jj = tid & 31;
        int r = (jj & 3) | ((jj >> 3) << 2);
        int h2 = (jj >> 2) & 1;
        float s = cs[(jbp2 * 2 + 0) * 32 + h2 * 16 + r] + cs[(jbp2 * 2 + 1) * 32 + h2 * 16 + r];
        lic[(size_t)bh * NN + jg * 64 + tid] = -__log2f(s);
    }
}

// ---------- pass 2: out^T = V^T @ P^T, P = exp2(sim*C + lic) ----------
__global__ __launch_bounds__(256, 4) void attn_k(
    const u16* __restrict__ qb, const u16* __restrict__ kb, const u16* __restrict__ vT,
    const float* __restrict__ lic, u16* __restrict__ ob)
{
    alignas(16) __shared__ char smem[36864];     // 2 x 16KB stage + 4KB lic
    const int tid = threadIdx.x;
    const int lane = tid & 63, wid = tid >> 6;
    const int il = lane & 31, hh = lane >> 5;
    const int n = blockIdx.x + 16 * blockIdx.y;
    const int L = (n & 7) * 128 + (n >> 3);
    const int ig = L & 15, bh = L >> 4;
    const int b = bh >> 3, h = bh & 7;
    const int ibp = wid & 1, jh = wid >> 1;
    const int ibase = ig * 64 + ibp * 32;
    char* licLds = smem + 32768;

    const u16* qRow = qb + (size_t)(b * NN + ibase + il) * DD + h * DH + hh * 8;
    short8 qf[4];
#pragma unroll
    for (int t = 0; t < 4; ++t) qf[t] = *(const short8*)(qRow + t * 16);

    // lic -> LDS (one-time; visible after first loop-top barrier)
    {
        float4 lv = *(const float4*)(lic + (size_t)bh * NN + tid * 4);
        *(float4*)(licLds + tid * 16) = lv;
    }

    const int line = tid >> 4, s15 = tid & 15;
    const int slot8 = (s15 & 7) ^ (line & 7);
    const int s16 = s15 ^ (line & 7);
    const u16* kg0 = kb + (size_t)(b * NN) * DD + h * DH;
    const u16* vg0 = vT + (size_t)h * DH * 8192 + b * NN;
    const char* pK0 = (const char*)(kg0 + (size_t)(line * 2 + (s15 >> 3)) * DD) + slot8 * 16;
    const char* pK1 = pK0 + 512 * DD * 2;
    const char* pV0 = (const char*)(vg0 + (size_t)(line * 4 + (s16 >> 2)) * 8192) + (s16 & 3) * 16;
    const char* pV1 = pV0 + 512 * 2;
    const int dstoff = tid * 16;

    auto stageKV = [&](char* buf, const char* k0, const char* k1,
                       const char* v0, const char* v1) {
        stage_gll(k0, buf + dstoff);
        stage_gll(k1, buf + 4096 + dstoff);
        stage_gll(v0, buf + 8192 + dstoff);
        stage_gll(v1, buf + 12288 + dstoff);
    };

    int ok[4], ov[2][2];
#pragma unroll
    for (int t = 0; t < 4; ++t) ok[t] = offF2(il, hh, t) + jh * 4096;
#pragma unroll
    for (int m = 0; m < 2; ++m)
#pragma unroll
        for (int tc = 0; tc < 2; ++tc) ov[m][tc] = offF4(il, hh, m, tc) + 8192 + jh * 4096;

    f32x16 oacc[2] = {};
    float rs4[4] = {0.f, 0.f, 0.f, 0.f};

    stageKV(smem, pK0, pK1, pV0, pV1);
    pK0 += 32768; pK1 += 32768; pV0 += 64; pV1 += 64;
    for (int p = 0; p < 16; ++p) {
        char* buf = smem + (p & 1) * 16384;
        __syncthreads();
        if (p < 15) {
            stageKV(smem + ((p + 1) & 1) * 16384, pK0, pK1, pV0, pV1);
            pK0 += 32768; pK1 += 32768; pV0 += 64; pV1 += 64;
        }
        const int jb = (jh * 16 + p) * 32;
        short8 kf[4];
#pragma unroll
        for (int t = 0; t < 4; ++t) kf[t] = *(const short8*)(buf + ok[t]);
        f32x16 sa = {};
        __builtin_amdgcn_s_setprio(1);
#pragma unroll
        for (int t = 0; t < 4; ++t)
            sa = __builtin_amdgcn_mfma_f32_32x32x16_bf16(kf[t], qf[t], sa, 0, 0, 0);
        __builtin_amdgcn_s_setprio(0);
        u32 pk[4][2];
#pragma unroll
        for (int s = 0; s < 4; ++s) {
            const float4 lc = *(const float4*)(licLds + ((jb + 8 * s + 4 * hh) << 2));
            const float p0 = fexp2(fmaf(sa[4 * s + 0], EXP2C, lc.x));
            const float p1 = fexp2(fmaf(sa[4 * s + 1], EXP2C, lc.y));
            const float p2 = fexp2(fmaf(sa[4 * s + 2], EXP2C, lc.z));
            const float p3 = fexp2(fmaf(sa[4 * s + 3], EXP2C, lc.w));
            rs4[s] += (p0 + p1) + (p2 + p3);
            pk[s][0] = cvtpk(p0, p1);
            pk[s][1] = cvtpk(p2, p3);
        }
        short8 vf[2][2];
#pragma unroll
        for (int m = 0; m < 2; ++m)
#pragma unroll
            for (int tc = 0; tc < 2; ++tc) vf[m][tc] = *(const short8*)(buf + ov[m][tc]);
#pragma unroll
        for (int tc = 0; tc < 2; ++tc) {
            int a0 = (int)pk[2 * tc][0], b0 = (int)pk[2 * tc + 1][0];
            int a1 = (int)pk[2 * tc][1], b1 = (int)pk[2 * tc + 1][1];
            asm("v_permlane32_swap_b32 %0, %1" : "+v"(a0), "+v"(b0));
            asm("v_permlane32_swap_b32 %0, %1" : "+v"(a1), "+v"(b1));
            u32x4 pw;
            pw.x = (u32)a0;   // k{0,1}
            pw.y = (u32)a1;   // k{2,3}
            pw.z = (u32)b0;   // k{4,5}
            pw.w = (u32)b1;   // k{6,7}
            const short8 pf = __builtin_bit_cast(short8, pw);
            __builtin_amdgcn_s_setprio(1);
#pragma unroll
            for (int m = 0; m < 2; ++m)
                oacc[m] = __builtin_amdgcn_mfma_f32_32x32x16_bf16(vf[m][tc], pf, oacc[m], 0, 0, 0);
            __builtin_amdgcn_s_setprio(0);
        }
    }

    float rs = (rs4[0] + rs4[1]) + (rs4[2] + rs4[3]);
    rs += __shfl_xor(rs, 32);
    __syncthreads();                             // staging dead; smem = combine buf
    float* cO = (float*)smem;                    // [2 ibp][32][64] = 16KB
    float* cR = (float*)(smem + 16384);          // [2 ibp][64]
    if (jh == 1) {
#pragma unroll
        for (int m = 0; m < 2; ++m)
#pragma unroll
            for (int r = 0; r < 16; ++r) cO[(ibp * 32 + m * 16 + r) * 64 + lane] = oacc[m][r];
        cR[ibp * 64 + lane] = rs;
    }
    __syncthreads();
    if (jh == 0) {
#pragma unroll
        for (int m = 0; m < 2; ++m)
#pragma unroll
            for (int r = 0; r < 16; ++r) oacc[m][r] += cO[(ibp * 32 + m * 16 + r) * 64 + lane];
        rs += cR[ibp * 64 + lane];
        const float inv = 1.0f / (rs + 1e-7f);
        u16* oRow = ob + (size_t)(b * NN + ibase + il) * DD + h * DH;
#pragma unroll
        for (int m = 0; m < 2; ++m) {
#pragma unroll
            for (int s = 0; s < 4; ++s) {
                ushort4v st;
#pragma unroll
                for (int g = 0; g < 4; ++g) st[g] = f2bf(oacc[m][4 * s + g] * inv);
                *(ushort4v*)(oRow + m * 32 + 8 * s + 4 * hh) = st;
            }
        }
    }
}

// ---------- launcher ----------

extern "C" void kernel_launch(void* const* d_in, const int* in_sizes, int n_in,
                              void* d_out, int out_size, void* d_ws, size_t ws_size,
                              hipStream_t stream)
{
    (void)in_sizes; (void)n_in; (void)out_size; (void)ws_size;
    const float* x   = (const float*)d_in[0];
    const float* ctx = (const float*)d_in[1];
    const float* Wq  = (const float*)d_in[2];
    const float* Wk  = (const float*)d_in[3];
    const float* Wv  = (const float*)d_in[4];
    const float* Wo  = (const float*)d_in[5];
    const float* bo  = (const float*)d_in[6];
    float* out = (float*)d_out;

    char* w = (char*)d_ws;
    const size_t SZBIG = 8192ull * 512 * 2;            // 8 MiB bf16 buffer
    u16* xb  = (u16*)(w);
    u16* cb  = (u16*)(w + SZBIG);
    u16* qb  = (u16*)(w + 2 * SZBIG);
    u16* kb  = (u16*)(w + 3 * SZBIG);
    u16* vT  = (u16*)(w + 4 * SZBIG);                  // [512][8192]
    u16* wb  = (u16*)(w + 5 * SZBIG);                  // wq,wk,wv,wo contiguous
    u16* wob = wb + 3 * 262144;
    float* lic = (float*)(w + 5 * SZBIG + 4 * 524288);
    u16* ob = xb;                                      // reuse (x dead after q GEMM)

    f2bf_all<<<9216, 256, 0, stream>>>(x, ctx, Wq, Wk, Wv, Wo, xb, cb, wb);

    gemm_qkv<<<dim3(4, 64, 3), 256, 0, stream>>>(xb, cb, wb, qb, kb, vT);

    colsum_k<<<dim3(16, 64), 256, 0, stream>>>(qb, kb, lic);
    attn_k  <<<dim3(16, 64), 256, 0, stream>>>(qb, kb, vT, lic, ob);

    gemm_out<<<dim3(4, 64), 256, 0, stream>>>(ob, wob, out, bo);
}

// Round 17
// 84.608 us; speedup vs baseline: 1.0220x; 1.0220x over previous
//
#include <hip/hip_runtime.h>

typedef __attribute__((ext_vector_type(8))) short short8;
typedef __attribute__((ext_vector_type(4))) float f32x4;
typedef __attribute__((ext_vector_type(16))) float f32x16;
typedef __attribute__((ext_vector_type(4))) unsigned short ushort4v;
typedef __attribute__((ext_vector_type(4))) unsigned int u32x4;
typedef unsigned short u16;
typedef unsigned int u32;

#define NN 1024
#define DD 512
#define DH 64
#define EXP2C 0.18033688f   /* 0.125 * log2(e) */

// ---------- helpers ----------

__device__ __forceinline__ u16 f2bf(float f) {
    unsigned u = __float_as_uint(f);
    u += 0x7fffu + ((u >> 16) & 1u);   // RNE
    return (u16)(u >> 16);
}

// native hardware exp2 (1 VALU op)
__device__ __forceinline__ float fexp2(float x) {
    float r;
    asm("v_exp_f32 %0, %1" : "=v"(r) : "v"(x));
    return r;
}

// packed fp32 pair -> bf16 pair (RNE), single VALU op
__device__ __forceinline__ u32 cvtpk(float a, float b) {
    u32 r;
    asm("v_cvt_pk_bf16_f32 %0, %1, %2" : "=v"(r) : "v"(a), "v"(b));
    return r;
}

__device__ __forceinline__ void stage_gll(const char* src, char* dst) {
    __builtin_amdgcn_global_load_lds(
        (const __attribute__((address_space(1))) unsigned int*)src,
        (__attribute__((address_space(3))) unsigned int*)dst, 16, 0, 0);
}

__device__ __forceinline__ short8 lds_ld128(const char* base, int row, int colbyte) {
    int off = (row * 128 + colbyte) ^ ((row & 7) << 4);
    return *(const short8*)(base + off);
}

__device__ __forceinline__ void stage128x64(const u16* g, int ldRow, char* lds,
                                            int wid, int lane) {
#pragma unroll
    for (int r = 0; r < 4; ++r) {
        int cidx = (r * 4 + wid) * 64 + lane;
        int row  = cidx >> 3;
        int ch   = (cidx & 7) ^ (row & 7);
        stage_gll((const char*)(g + row * ldRow) + ch * 16, lds + (r * 4 + wid) * 1024);
    }
}

// fold-2 tile (32 rows x 128B, 4KB): lane-offset for (il,hh,t) — p-invariant
__device__ __forceinline__ int offF2(int il, int hh, int t) {
    int c0 = t * 2 + hh;
    return ((il >> 1) << 8) + ((il & 1) << 7) + ((c0 ^ ((il >> 1) & 7)) << 4);
}

// fold-4 tile (64 rows x 64B, 4KB): lane-offset for (il,hh,m,tc)
__device__ __forceinline__ int offF4(int il, int hh, int m, int tc) {
    int c0 = tc * 2 + hh;
    int line = m * 8 + (il >> 2);
    int s16 = (((il & 3) << 2) + c0) ^ ((il >> 2) & 7);
    return line * 256 + (s16 << 4);
}

// ---------- fused fp32 -> bf16 convert ----------
__global__ void f2bf_all(const float* __restrict__ x, const float* __restrict__ ctx,
                         const float* __restrict__ Wq, const float* __restrict__ Wk,
                         const float* __restrict__ Wv, const float* __restrict__ Wo,
                         u16* __restrict__ xb, u16* __restrict__ cb,
                         u16* __restrict__ wb) {
    int i = blockIdx.x * blockDim.x + threadIdx.x;   // float4 index, 2359296 total
    const float* src;
    u16* dst;
    int off;
    if (i < 1048576)      { src = x;   dst = xb; off = i; }
    else if (i < 2097152) { src = ctx; dst = cb; off = i - 1048576; }
    else {
        int wi = i - 2097152;
        int which = wi >> 16;
        off = wi & 65535;
        dst = wb + (size_t)which * 262144;
        src = (which == 0) ? Wq : (which == 1) ? Wk : (which == 2) ? Wv : Wo;
    }
    float4 v = ((const float4*)src)[off];
    ushort4v o;
    o.x = f2bf(v.x); o.y = f2bf(v.y); o.z = f2bf(v.z); o.w = f2bf(v.w);
    *(ushort4v*)(dst + (size_t)off * 4) = o;
}

// ---------- fused QKV projection GEMMs ----------
// serial 32KB stage, 3 blocks/CU: all 768 blocks co-resident (no capacity tail)
__global__ __launch_bounds__(256, 3) void gemm_qkv(
    const u16* __restrict__ xb, const u16* __restrict__ cb, const u16* __restrict__ wb,
    u16* __restrict__ qb, u16* __restrict__ kb, u16* __restrict__ vT)
{
    __shared__ char As[16384];
    __shared__ char Bs[16384];
    const int z = blockIdx.z;
    const u16* A = (z == 0) ? xb : cb;
    const u16* B = wb + (size_t)z * 262144;
    const int lane = threadIdx.x & 63;
    const int wid  = threadIdx.x >> 6;
    const int wr = wid >> 1, wc = wid & 1;
    const int n = blockIdx.x + 4 * blockIdx.y;
    const int L = (n & 7) * 32 + (n >> 3);
    const int rowBase = (L >> 2) * 128;
    const int colBase = (L & 3) * 128;

    f32x4 acc[4][4] = {};
    for (int kt = 0; kt < 8; ++kt) {
        __syncthreads();
        stage128x64(A + (size_t)rowBase * DD + kt * 64, DD, As, wid, lane);
        stage128x64(B + (size_t)colBase * DD + kt * 64, DD, Bs, wid, lane);
        __syncthreads();
#pragma unroll
        for (int kk = 0; kk < 2; ++kk) {
            const int cbb = kk * 64 + (lane >> 4) * 16;
            short8 af[4], bf[4];
#pragma unroll
            for (int m = 0; m < 4; ++m) af[m] = lds_ld128(As, wr * 64 + m * 16 + (lane & 15), cbb);
#pragma unroll
            for (int q = 0; q < 4; ++q) bf[q] = lds_ld128(Bs, wc * 64 + q * 16 + (lane & 15), cbb);
#pragma unroll
            for (int m = 0; m < 4; ++m) {
#pragma unroll
                for (int q = 0; q < 4; ++q)
                    acc[m][q] = __builtin_amdgcn_mfma_f32_16x16x32_bf16(af[m], bf[q], acc[m][q], 0, 0, 0);
            }
        }
    }
#pragma unroll
    for (int m = 0; m < 4; ++m) {
#pragma unroll
        for (int q = 0; q < 4; ++q) {
            const int r0 = rowBase + wr * 64 + m * 16 + ((lane >> 4) << 2);
            const int c  = colBase + wc * 64 + q * 16 + (lane & 15);
            if (z < 2) {
                u16* O = z ? kb : qb;
#pragma unroll
                for (int g = 0; g < 4; ++g) O[(size_t)(r0 + g) * DD + c] = f2bf(acc[m][q][g]);
            } else {
                ushort4v pk;
#pragma unroll
                for (int g = 0; g < 4; ++g) pk[g] = f2bf(acc[m][q][g]);
                *(ushort4v*)(vT + (size_t)c * 8192 + r0) = pk;
            }
        }
    }
}

// ---------- final GEMM: fp32 out + bias (double-buffered LDS pipeline) ----------
__global__ __launch_bounds__(256, 2) void gemm_out(
    const u16* __restrict__ A, const u16* __restrict__ B,
    float* __restrict__ Out, const float* __restrict__ bias)
{
    alignas(16) __shared__ char smem[65536];
    const int lane = threadIdx.x & 63;
    const int wid  = threadIdx.x >> 6;
    const int wr = wid >> 1, wc = wid & 1;
    const int n = blockIdx.x + 4 * blockIdx.y;
    const int L = (n & 7) * 32 + (n >> 3);
    const int rowBase = (L >> 2) * 128;
    const int colBase = (L & 3) * 128;
    const u16* Abase = A + (size_t)rowBase * DD;
    const u16* Bbase = B + (size_t)colBase * DD;

    f32x4 acc[4][4] = {};
    stage128x64(Abase, DD, smem, wid, lane);
    stage128x64(Bbase, DD, smem + 32768, wid, lane);
    for (int kt = 0; kt < 8; ++kt) {
        __syncthreads();
        char* curA = smem + (kt & 1) * 16384;
        char* curB = smem + 32768 + (kt & 1) * 16384;
        if (kt < 7) {
            stage128x64(Abase + (kt + 1) * 64, DD, smem + ((kt + 1) & 1) * 16384, wid, lane);
            stage128x64(Bbase + (kt + 1) * 64, DD, smem + 32768 + ((kt + 1) & 1) * 16384, wid, lane);
        }
#pragma unroll
        for (int kk = 0; kk < 2; ++kk) {
            const int cbb = kk * 64 + (lane >> 4) * 16;
            short8 af[4], bf[4];
#pragma unroll
            for (int m = 0; m < 4; ++m) af[m] = lds_ld128(curA, wr * 64 + m * 16 + (lane & 15), cbb);
#pragma unroll
            for (int q = 0; q < 4; ++q) bf[q] = lds_ld128(curB, wc * 64 + q * 16 + (lane & 15), cbb);
#pragma unroll
            for (int m = 0; m < 4; ++m) {
#pragma unroll
                for (int q = 0; q < 4; ++q)
                    acc[m][q] = __builtin_amdgcn_mfma_f32_16x16x32_bf16(af[m], bf[q], acc[m][q], 0, 0, 0);
            }
        }
    }
#pragma unroll
    for (int m = 0; m < 4; ++m) {
#pragma unroll
        for (int q = 0; q < 4; ++q) {
            const int r0 = rowBase + wr * 64 + m * 16 + ((lane >> 4) << 2);
            const int c  = colBase + wc * 64 + q * 16 + (lane & 15);
            const float bb = bias[c];
#pragma unroll
            for (int g = 0; g < 4; ++g) Out[(size_t)(r0 + g) * DD + c] = acc[m][q][g] + bb;
        }
    }
}

// ---------- pass 1: lic[j] = -log2( sum_i exp(sim) ) ----------
__global__ __launch_bounds__(256, 4) void colsum_k(
    const u16* __restrict__ qb, const u16* __restrict__ kb, float* __restrict__ lic)
{
    alignas(16) __shared__ char smem[16384];
    __shared__ float cs[128];
    const int tid = threadIdx.x;
    const int lane = tid & 63, wid = tid >> 6;
    const int il = lane & 31, hh = lane >> 5;
    const int n = blockIdx.x + 16 * blockIdx.y;
    const int L = (n & 7) * 128 + (n >> 3);
    const int jg = L & 15, bh = L >> 4;
    const int b = bh >> 3, h = bh & 7;
    const int jbp = wid & 1, ih = wid >> 1;
    const int jbase = jg * 64 + jbp * 32;

    const u16* kRow = kb + (size_t)(b * NN + jbase + il) * DD + h * DH + hh * 8;
    short8 kf[4];
#pragma unroll
    for (int t = 0; t < 4; ++t) kf[t] = *(const short8*)(kRow + t * 16);

    const int line = tid >> 4, s15 = tid & 15;
    const int slot8 = (s15 & 7) ^ (line & 7);
    const u16* qg0 = qb + (size_t)(b * NN) * DD + h * DH;
    const char* pQ0 = (const char*)(qg0 + (size_t)(line * 2 + (s15 >> 3)) * DD) + slot8 * 16;
    const char* pQ1 = pQ0 + 512 * DD * 2;
    const int dstoff = tid * 16;

    auto stageQ = [&](char* buf, const char* q0, const char* q1) {
        stage_gll(q0, buf + dstoff);
        stage_gll(q1, buf + 4096 + dstoff);
    };

    int oq[4];
#pragma unroll
    for (int t = 0; t < 4; ++t) oq[t] = offF2(il, hh, t) + ih * 4096;

    float cp[16] = {};
    stageQ(smem, pQ0, pQ1);
    pQ0 += 32768; pQ1 += 32768;
    for (int p = 0; p < 16; ++p) {
        char* buf = smem + (p & 1) * 8192;
        __syncthreads();
        if (p < 15) {
            stageQ(smem + ((p + 1) & 1) * 8192, pQ0, pQ1);
            pQ0 += 32768; pQ1 += 32768;
        }
        short8 qf[4];
#pragma unroll
        for (int t = 0; t < 4; ++t) qf[t] = *(const short8*)(buf + oq[t]);
        f32x16 sa = {};
#pragma unroll
        for (int t = 0; t < 4; ++t)
            sa = __builtin_amdgcn_mfma_f32_32x32x16_bf16(kf[t], qf[t], sa, 0, 0, 0);
#pragma unroll
        for (int r = 0; r < 16; ++r) cp[r] += fexp2(sa[r] * EXP2C);
    }
#pragma unroll
    for (int r = 0; r < 16; ++r) {
        cp[r] += __shfl_xor(cp[r], 1);
        cp[r] += __shfl_xor(cp[r], 2);
        cp[r] += __shfl_xor(cp[r], 4);
        cp[r] += __shfl_xor(cp[r], 8);
        cp[r] += __shfl_xor(cp[r], 16);
    }
    if (il == 0) {
#pragma unroll
        for (int r = 0; r < 16; ++r) cs[(jbp * 2 + ih) * 32 + hh * 16 + r] = cp[r];
    }
    __syncthreads();
    if (tid < 64) {
        int jbp2 = tid >> 5, jj = tid & 31;
        int r = (jj & 3) | ((jj >> 3) << 2);
        int h2 = (jj >> 2) & 1;
        float s = cs[(jbp2 * 2 + 0) * 32 + h2 * 16 + r] + cs[(jbp2 * 2 + 1) * 32 + h2 * 16 + r];
        lic[(size_t)bh * NN + jg * 64 + tid] = -__log2f(s);
    }
}

// ---------- pass 2: out^T = V^T @ P^T, P = exp2(sim*C + lic) ----------
__global__ __launch_bounds__(256, 4) void attn_k(
    const u16* __restrict__ qb, const u16* __restrict__ kb, const u16* __restrict__ vT,
    const float* __restrict__ lic, u16* __restrict__ ob)
{
    alignas(16) __shared__ char smem[36864];     // 2 x 16KB stage + 4KB lic
    const int tid = threadIdx.x;
    const int lane = tid & 63, wid = tid >> 6;
    const int il = lane & 31, hh = lane >> 5;
    const int n = blockIdx.x + 16 * blockIdx.y;
    const int L = (n & 7) * 128 + (n >> 3);
    const int ig = L & 15, bh = L >> 4;
    const int b = bh >> 3, h = bh & 7;
    const int ibp = wid & 1, jh = wid >> 1;
    const int ibase = ig * 64 + ibp * 32;
    char* licLds = smem + 32768;

    const u16* qRow = qb + (size_t)(b * NN + ibase + il) * DD + h * DH + hh * 8;
    short8 qf[4];
#pragma unroll
    for (int t = 0; t < 4; ++t) qf[t] = *(const short8*)(qRow + t * 16);

    // lic -> LDS (one-time; visible after first loop-top barrier)
    {
        float4 lv = *(const float4*)(lic + (size_t)bh * NN + tid * 4);
        *(float4*)(licLds + tid * 16) = lv;
    }

    const int line = tid >> 4, s15 = tid & 15;
    const int slot8 = (s15 & 7) ^ (line & 7);
    const int s16 = s15 ^ (line & 7);
    const u16* kg0 = kb + (size_t)(b * NN) * DD + h * DH;
    const u16* vg0 = vT + (size_t)h * DH * 8192 + b * NN;
    const char* pK0 = (const char*)(kg0 + (size_t)(line * 2 + (s15 >> 3)) * DD) + slot8 * 16;
    const char* pK1 = pK0 + 512 * DD * 2;
    const char* pV0 = (const char*)(vg0 + (size_t)(line * 4 + (s16 >> 2)) * 8192) + (s16 & 3) * 16;
    const char* pV1 = pV0 + 512 * 2;
    const int dstoff = tid * 16;

    auto stageKV = [&](char* buf, const char* k0, const char* k1,
                       const char* v0, const char* v1) {
        stage_gll(k0, buf + dstoff);
        stage_gll(k1, buf + 4096 + dstoff);
        stage_gll(v0, buf + 8192 + dstoff);
        stage_gll(v1, buf + 12288 + dstoff);
    };

    int ok[4], ov[2][2];
#pragma unroll
    for (int t = 0; t < 4; ++t) ok[t] = offF2(il, hh, t) + jh * 4096;
#pragma unroll
    for (int m = 0; m < 2; ++m)
#pragma unroll
        for (int tc = 0; tc < 2; ++tc) ov[m][tc] = offF4(il, hh, m, tc) + 8192 + jh * 4096;

    f32x16 oacc[2] = {};
    float rs4[4] = {0.f, 0.f, 0.f, 0.f};

    stageKV(smem, pK0, pK1, pV0, pV1);
    pK0 += 32768; pK1 += 32768; pV0 += 64; pV1 += 64;
    for (int p = 0; p < 16; ++p) {
        char* buf = smem + (p & 1) * 16384;
        __syncthreads();
        if (p < 15) {
            stageKV(smem + ((p + 1) & 1) * 16384, pK0, pK1, pV0, pV1);
            pK0 += 32768; pK1 += 32768; pV0 += 64; pV1 += 64;
        }
        const int jb = (jh * 16 + p) * 32;
        short8 kf[4];
#pragma unroll
        for (int t = 0; t < 4; ++t) kf[t] = *(const short8*)(buf + ok[t]);
        f32x16 sa = {};
#pragma unroll
        for (int t = 0; t < 4; ++t)
            sa = __builtin_amdgcn_mfma_f32_32x32x16_bf16(kf[t], qf[t], sa, 0, 0, 0);
        u32 pk[4][2];
#pragma unroll
        for (int s = 0; s < 4; ++s) {
            const float4 lc = *(const float4*)(licLds + ((jb + 8 * s + 4 * hh) << 2));
            const float p0 = fexp2(fmaf(sa[4 * s + 0], EXP2C, lc.x));
            const float p1 = fexp2(fmaf(sa[4 * s + 1], EXP2C, lc.y));
            const float p2 = fexp2(fmaf(sa[4 * s + 2], EXP2C, lc.z));
            const float p3 = fexp2(fmaf(sa[4 * s + 3], EXP2C, lc.w));
            rs4[s] += (p0 + p1) + (p2 + p3);
            pk[s][0] = cvtpk(p0, p1);
            pk[s][1] = cvtpk(p2, p3);
        }
        short8 vf[2][2];
#pragma unroll
        for (int m = 0; m < 2; ++m)
#pragma unroll
            for (int tc = 0; tc < 2; ++tc) vf[m][tc] = *(const short8*)(buf + ov[m][tc]);
#pragma unroll
        for (int tc = 0; tc < 2; ++tc) {
            int a0 = (int)pk[2 * tc][0], b0 = (int)pk[2 * tc + 1][0];
            int a1 = (int)pk[2 * tc][1], b1 = (int)pk[2 * tc + 1][1];
            asm("v_permlane32_swap_b32 %0, %1" : "+v"(a0), "+v"(b0));
            asm("v_permlane32_swap_b32 %0, %1" : "+v"(a1), "+v"(b1));
            u32x4 pw;
            pw.x = (u32)a0;   // k{0,1}
            pw.y = (u32)a1;   // k{2,3}
            pw.z = (u32)b0;   // k{4,5}
            pw.w = (u32)b1;   // k{6,7}
            const short8 pf = __builtin_bit_cast(short8, pw);
#pragma unroll
            for (int m = 0; m < 2; ++m)
                oacc[m] = __builtin_amdgcn_mfma_f32_32x32x16_bf16(vf[m][tc], pf, oacc[m], 0, 0, 0);
        }
    }

    float rs = (rs4[0] + rs4[1]) + (rs4[2] + rs4[3]);
    rs += __shfl_xor(rs, 32);
    __syncthreads();                             // staging dead; smem = combine buf
    float* cO = (float*)smem;                    // [2 ibp][32][64] = 16KB
    float* cR = (float*)(smem + 16384);          // [2 ibp][64]
    if (jh == 1) {
#pragma unroll
        for (int m = 0; m < 2; ++m)
#pragma unroll
            for (int r = 0; r < 16; ++r) cO[(ibp * 32 + m * 16 + r) * 64 + lane] = oacc[m][r];
        cR[ibp * 64 + lane] = rs;
    }
    __syncthreads();
    if (jh == 0) {
#pragma unroll
        for (int m = 0; m < 2; ++m)
#pragma unroll
            for (int r = 0; r < 16; ++r) oacc[m][r] += cO[(ibp * 32 + m * 16 + r) * 64 + lane];
        rs += cR[ibp * 64 + lane];
        const float inv = 1.0f / (rs + 1e-7f);
        u16* oRow = ob + (size_t)(b * NN + ibase + il) * DD + h * DH;
#pragma unroll
        for (int m = 0; m < 2; ++m) {
#pragma unroll
            for (int s = 0; s < 4; ++s) {
                ushort4v st;
#pragma unroll
                for (int g = 0; g < 4; ++g) st[g] = f2bf(oacc[m][4 * s + g] * inv);
                *(ushort4v*)(oRow + m * 32 + 8 * s + 4 * hh) = st;
            }
        }
    }
}

// ---------- launcher ----------

extern "C" void kernel_launch(void* const* d_in, const int* in_sizes, int n_in,
                              void* d_out, int out_size, void* d_ws, size_t ws_size,
                              hipStream_t stream)
{
    (void)in_sizes; (void)n_in; (void)out_size; (void)ws_size;
    const float* x   = (const float*)d_in[0];
    const float* ctx = (const float*)d_in[1];
    const float* Wq  = (const float*)d_in[2];
    const float* Wk  = (const float*)d_in[3];
    const float* Wv  = (const float*)d_in[4];
    const float* Wo  = (const float*)d_in[5];
    const float* bo  = (const float*)d_in[6];
    float* out = (float*)d_out;

    char* w = (char*)d_ws;
    const size_t SZBIG = 8192ull * 512 * 2;            // 8 MiB bf16 buffer
    u16* xb  = (u16*)(w);
    u16* cb  = (u16*)(w + SZBIG);
    u16* qb  = (u16*)(w + 2 * SZBIG);
    u16* kb  = (u16*)(w + 3 * SZBIG);
    u16* vT  = (u16*)(w + 4 * SZBIG);                  // [512][8192]
    u16* wb  = (u16*)(w + 5 * SZBIG);                  // wq,wk,wv,wo contiguous
    u16* wob = wb + 3 * 262144;
    float* lic = (float*)(w + 5 * SZBIG + 4 * 524288);
    u16* ob = xb;                                      // reuse (x dead after q GEMM)

    f2bf_all<<<9216, 256, 0, stream>>>(x, ctx, Wq, Wk, Wv, Wo, xb, cb, wb);

    gemm_qkv<<<dim3(4, 64, 3), 256, 0, stream>>>(xb, cb, wb, qb, kb, vT);

    colsum_k<<<dim3(16, 64), 256, 0, stream>>>(qb, kb, lic);
    attn_k  <<<dim3(16, 64), 256, 0, stream>>>(qb, kb, vT, lic, ob);

    gemm_out<<<dim3(4, 64), 256, 0, stream>>>(ob, wob, out, bo);
}